// Round 2
// baseline (5475.108 us; speedup 1.0000x reference)
//
#include <hip/hip_runtime.h>
#include <stdint.h>

// ---------------- bf16 helpers -------------------------------------------
__device__ __forceinline__ float bf2f(uint16_t u) {
    uint32_t x = ((uint32_t)u) << 16;
    float f;
    __builtin_memcpy(&f, &x, 4);
    return f;
}
__device__ __forceinline__ uint16_t f2bf(float f) {
    uint32_t u;
    __builtin_memcpy(&u, &f, 4);
    uint32_t r = (u + 0x7fffu + ((u >> 16) & 1u)) >> 16;  // RNE
    return (uint16_t)r;
}
__device__ __forceinline__ float loadf(const float* p) { return *p; }
__device__ __forceinline__ float loadf(const uint16_t* p) { return bf2f(*p); }

typedef __attribute__((ext_vector_type(8))) short short8;   // 8 bf16 (MFMA A/B)
typedef __attribute__((ext_vector_type(4))) float floatx4;  // MFMA C/D

// ---------------- dtype detector ------------------------------------------
// True bf16 N(0,1): exponent field in [96,159] for ~all elements.
// f32 reinterpreted as u16: even idx = mantissa bits (uniform exp, ~25% sane),
// odd idx = true bf16-like (sane) -> total ~62%. Threshold 448/512 = 87.5%.
__global__ void detect_dtype(const uint16_t* __restrict__ x, int* __restrict__ flag) {
    int lane = threadIdx.x;  // 64 threads
    int cnt = 0;
    for (int i = 0; i < 8; ++i) {
        uint16_t u = x[lane * 8 + i];
        int e = (u >> 7) & 0xff;
        if (u == 0 || (e >= 96 && e <= 159)) ++cnt;
    }
    for (int off = 32; off; off >>= 1) cnt += __shfl_down(cnt, off);
    if (lane == 0) *flag = (cnt >= 448) ? 1 : 0;  // 1 = bf16 inputs, 0 = f32
}

// ---------------- Cayley via Newton-Schulz (division-free) -----------------
// M = I+S (global f32 scratch), Y0 = I-S (LDS). Y <- Y(2I - M Y) x8.
// Q = Y(2I-M) = 2Y - Y*M.  rho(S) <= ~0.51 -> guaranteed quadratic conv.
template <typename T>
__global__ __launch_bounds__(256) void cayley_ns(const T* __restrict__ W,
                                                 float* __restrict__ out,
                                                 float* __restrict__ Mg_all, int n,
                                                 const int* __restrict__ flag, int want) {
    if (*flag != want) return;
    __shared__ float Ys[80 * 81];
    __shared__ float Ts[80 * 81];
    const int tid = threadIdx.x;
    const int st = 81;
    const T* Wb = W + (size_t)blockIdx.x * n * n;
    float* Mg = Mg_all + (size_t)blockIdx.x * n * n;
    float* O = out + (size_t)blockIdx.x * n * n;
    const int nel = n * n;
    for (int e = tid; e < nel; e += 256) {
        int i = e / n, j = e - i * n;
        float s = loadf(Wb + i * n + j) - loadf(Wb + j * n + i);
        float idt = (i == j) ? 1.f : 0.f;
        Mg[i * n + j] = idt + s;   // M = I+S
        Ys[i * st + j] = idt - s;  // Y0 = 2I-M = I-S
    }
    __syncthreads();
    float r[26];  // <= ceil(80*80/256) = 25 elements per thread
    for (int it = 0; it < 8; ++it) {
        // Ts = 2I - M*Y
        for (int e = tid; e < nel; e += 256) {
            int i = e / n, j = e - i * n;
            float s = 0.f;
            for (int k = 0; k < n; ++k) s += Mg[i * n + k] * Ys[k * st + j];
            Ts[i * st + j] = ((i == j) ? 2.f : 0.f) - s;
        }
        __syncthreads();
        // r = Y*Ts (into regs), then write back to Y
        int cnt = 0;
        for (int e = tid; e < nel; e += 256, ++cnt) {
            int i = e / n, j = e - i * n;
            float s = 0.f;
            for (int k = 0; k < n; ++k) s += Ys[i * st + k] * Ts[k * st + j];
            r[cnt] = s;
        }
        __syncthreads();
        cnt = 0;
        for (int e = tid; e < nel; e += 256, ++cnt) {
            int i = e / n, j = e - i * n;
            Ys[i * st + j] = r[cnt];
        }
        __syncthreads();
    }
    // Q = 2Y - Y*M
    for (int e = tid; e < nel; e += 256) {
        int i = e / n, j = e - i * n;
        float s = 0.f;
        for (int k = 0; k < n; ++k) s += Ys[i * st + k] * Mg[k * n + j];
        O[i * n + j] = 2.f * Ys[i * st + j] - s;
    }
}

// ------- fused fold: WeffT[o][k*bdim+b] = sc[o]*sum_c A[k][b][c]*t[c],
//         t[c] = sum_j B[c][k][j]*W[o][j*bdim+c].  One block per o. ---------
template <typename T>
__global__ __launch_bounds__(256) void build_weff2(const T* __restrict__ W,
                                                   const float* __restrict__ Ac,
                                                   const float* __restrict__ Bc,
                                                   const T* __restrict__ scale,
                                                   uint16_t* __restrict__ WeffT,
                                                   int bdim, int Din,
                                                   const int* __restrict__ flag, int want) {
    if (*flag != want) return;
    __shared__ float Wrow[1280];
    __shared__ float tvec[80];
    const int o = blockIdx.x, tid = threadIdx.x;
    for (int i = tid; i < Din; i += 256) Wrow[i] = loadf(W + (size_t)o * Din + i);
    __syncthreads();
    float sc = loadf(scale + o);
    for (int k = 0; k < 16; ++k) {
        if (tid < bdim) {
            const float* Bm = Bc + tid * 256 + k * 16;  // B[c=tid][k][j]
            float s = 0.f;
#pragma unroll
            for (int j = 0; j < 16; ++j) s += Bm[j] * Wrow[j * bdim + tid];
            tvec[tid] = s;
        }
        __syncthreads();
        if (tid < bdim) {  // tid = beta
            const float* Am = Ac + ((size_t)k * bdim + tid) * bdim;
            float s = 0.f;
            for (int c = 0; c < bdim; ++c) s += Am[c] * tvec[c];
            WeffT[(size_t)o * Din + k * bdim + tid] = f2bf(s * sc);
        }
        __syncthreads();
    }
}

// ---------------- C[M][N] = A[M][K]*Bt[N][K]^T (+bias), bf16 MFMA ----------
// A dtype templated (f32 converted to bf16 during LDS staging). B always bf16.
// Grid: (x = N tiles, y = M tiles) so consecutive blocks share the A strip.
#define BM 128
#define BN 128
#define BKK 32
template <typename T>
__global__ __launch_bounds__(256) void gemm_bt(const T* __restrict__ A,
                                               const uint16_t* __restrict__ Bt,
                                               void* __restrict__ Cv,
                                               const void* __restrict__ biasv,
                                               int M, int N, int K,
                                               const int* __restrict__ flag, int want,
                                               int flagio) {
    if (want >= 0 && *flag != want) return;
    const bool io32 = flagio && (*flag == 0);
    __shared__ uint16_t As[BM * BKK];
    __shared__ uint16_t Bs[BN * BKK];
    const int n0 = blockIdx.x * BN, m0 = blockIdx.y * BM;
    const int tid = threadIdx.x;
    const int wave = tid >> 6, lane = tid & 63;
    const int wm = (wave & 1) * 64, wn = (wave >> 1) * 64;
    const int l16 = lane & 15, quad = lane >> 4;

    floatx4 acc[4][4];
#pragma unroll
    for (int i = 0; i < 4; ++i)
#pragma unroll
        for (int j = 0; j < 4; ++j) {
            floatx4 z = {0.f, 0.f, 0.f, 0.f};
            acc[i][j] = z;
        }

    for (int k0 = 0; k0 < K; k0 += BKK) {
        // B staging: 512 x 16B chunks
#pragma unroll
        for (int r = 0; r < 2; ++r) {
            int chunk = tid + r * 256;
            int row = chunk >> 2, c4 = chunk & 3;
            *(uint4*)(&Bs[row * BKK + c4 * 8]) =
                *(const uint4*)(Bt + (size_t)(n0 + row) * K + k0 + c4 * 8);
        }
        // A staging
        if constexpr (sizeof(T) == 2) {
#pragma unroll
            for (int r = 0; r < 2; ++r) {
                int chunk = tid + r * 256;
                int row = chunk >> 2, c4 = chunk & 3;
                int ar = m0 + row;
                ar = ar < M ? ar : M - 1;  // ragged M: clamp load, mask store
                *(uint4*)(&As[row * BKK + c4 * 8]) =
                    *(const uint4*)(A + (size_t)ar * K + k0 + c4 * 8);
            }
        } else {
#pragma unroll
            for (int r = 0; r < 4; ++r) {
                int chunk = tid + r * 256;  // 1024 x float4 chunks
                int row = chunk >> 3, c8 = chunk & 7;
                int ar = m0 + row;
                ar = ar < M ? ar : M - 1;
                float4 v = *(const float4*)(A + (size_t)ar * K + k0 + c8 * 4);
                uint32_t p0 = (uint32_t)f2bf(v.x) | ((uint32_t)f2bf(v.y) << 16);
                uint32_t p1 = (uint32_t)f2bf(v.z) | ((uint32_t)f2bf(v.w) << 16);
                *(uint2*)(&As[row * BKK + c8 * 4]) = make_uint2(p0, p1);
            }
        }
        __syncthreads();
        short8 af[4], bfr[4];
#pragma unroll
        for (int i = 0; i < 4; ++i)
            af[i] = *(const short8*)(&As[(wm + i * 16 + l16) * BKK + quad * 8]);
#pragma unroll
        for (int j = 0; j < 4; ++j)
            bfr[j] = *(const short8*)(&Bs[(wn + j * 16 + l16) * BKK + quad * 8]);
#pragma unroll
        for (int i = 0; i < 4; ++i)
#pragma unroll
            for (int j = 0; j < 4; ++j)
                acc[i][j] = __builtin_amdgcn_mfma_f32_16x16x32_bf16(af[i], bfr[j],
                                                                    acc[i][j], 0, 0, 0);
        __syncthreads();
    }

    // C/D layout: col = lane&15, row = quad*4 + reg  [m89/m91-verified]
#pragma unroll
    for (int i = 0; i < 4; ++i) {
#pragma unroll
        for (int r = 0; r < 4; ++r) {
            int row = m0 + wm + i * 16 + quad * 4 + r;
            if (row < M) {
#pragma unroll
                for (int j = 0; j < 4; ++j) {
                    int col = n0 + wn + j * 16 + l16;
                    float v = acc[i][j][r];
                    if (biasv)
                        v += io32 ? ((const float*)biasv)[col]
                                  : bf2f(((const uint16_t*)biasv)[col]);
                    size_t idx = (size_t)row * N + col;
                    if (io32)
                        ((float*)Cv)[idx] = v;
                    else
                        ((uint16_t*)Cv)[idx] = f2bf(v);
                }
            }
        }
    }
}

// ---------------- attention: T=77, dh=64, per-thread q-row -----------------
__global__ __launch_bounds__(256) void attn_fused(const uint16_t* __restrict__ kbuf,
                                                  const uint16_t* __restrict__ vbuf,
                                                  uint16_t* __restrict__ qbuf,
                                                  int B, int S) {
    __shared__ float KT[64 * 80];  // [d][t], t padded 77->80, pads zeroed
    __shared__ float VT[64 * 80];
    const int b = blockIdx.z, h = blockIdx.y;
    const int tid = threadIdx.x;
    for (int e = tid; e < 64 * 80; e += 256) {
        int d = e / 80, t = e - d * 80;
        float kk = 0.f, vv = 0.f;
        if (t < 77) {
            size_t gi = ((size_t)(b * 77 + t)) * 1280 + h * 64 + d;
            kk = bf2f(kbuf[gi]);
            vv = bf2f(vbuf[gi]);
        }
        KT[e] = kk;
        VT[e] = vv;
    }
    __syncthreads();
    const int s = blockIdx.x * 256 + tid;
    uint16_t* qrow = qbuf + ((size_t)b * S + s) * 1280 + h * 64;

    float sc[80];
#pragma unroll
    for (int t = 0; t < 80; ++t) sc[t] = 0.f;

    const uint4* qp = (const uint4*)qrow;
#pragma unroll 1
    for (int c = 0; c < 8; ++c) {
        uint4 qv = qp[c];
        float qf[8];
        qf[0] = bf2f((uint16_t)(qv.x & 0xffff)); qf[1] = bf2f((uint16_t)(qv.x >> 16));
        qf[2] = bf2f((uint16_t)(qv.y & 0xffff)); qf[3] = bf2f((uint16_t)(qv.y >> 16));
        qf[4] = bf2f((uint16_t)(qv.z & 0xffff)); qf[5] = bf2f((uint16_t)(qv.z >> 16));
        qf[6] = bf2f((uint16_t)(qv.w & 0xffff)); qf[7] = bf2f((uint16_t)(qv.w >> 16));
#pragma unroll
        for (int dd = 0; dd < 8; ++dd) {
            const float* Kr = &KT[(c * 8 + dd) * 80];
#pragma unroll
            for (int t4 = 0; t4 < 20; ++t4) {
                float4 k4 = *(const float4*)(Kr + 4 * t4);
                sc[4 * t4 + 0] = fmaf(qf[dd], k4.x, sc[4 * t4 + 0]);
                sc[4 * t4 + 1] = fmaf(qf[dd], k4.y, sc[4 * t4 + 1]);
                sc[4 * t4 + 2] = fmaf(qf[dd], k4.z, sc[4 * t4 + 2]);
                sc[4 * t4 + 3] = fmaf(qf[dd], k4.w, sc[4 * t4 + 3]);
            }
        }
    }

    float mx = -1e30f;
#pragma unroll
    for (int t = 0; t < 77; ++t) {
        sc[t] *= 0.125f;  // dh^-0.5
        mx = fmaxf(mx, sc[t]);
    }
    float den = 0.f;
#pragma unroll
    for (int t = 0; t < 77; ++t) {
        float p = __expf(sc[t] - mx);
        sc[t] = p;
        den += p;
    }
    float rden = 1.f / den;
#pragma unroll
    for (int t = 0; t < 77; ++t) sc[t] *= rden;
    sc[77] = sc[78] = sc[79] = 0.f;

#pragma unroll 1
    for (int c = 0; c < 8; ++c) {
        uint32_t pk[4];
#pragma unroll
        for (int dd = 0; dd < 8; dd += 2) {
            float o0 = 0.f, o1 = 0.f;
            const float* V0 = &VT[(c * 8 + dd) * 80];
            const float* V1 = &VT[(c * 8 + dd + 1) * 80];
#pragma unroll
            for (int t4 = 0; t4 < 20; ++t4) {
                float4 v0 = *(const float4*)(V0 + 4 * t4);
                float4 v1 = *(const float4*)(V1 + 4 * t4);
                o0 = fmaf(sc[4 * t4 + 0], v0.x, o0);
                o0 = fmaf(sc[4 * t4 + 1], v0.y, o0);
                o0 = fmaf(sc[4 * t4 + 2], v0.z, o0);
                o0 = fmaf(sc[4 * t4 + 3], v0.w, o0);
                o1 = fmaf(sc[4 * t4 + 0], v1.x, o1);
                o1 = fmaf(sc[4 * t4 + 1], v1.y, o1);
                o1 = fmaf(sc[4 * t4 + 2], v1.z, o1);
                o1 = fmaf(sc[4 * t4 + 3], v1.w, o1);
            }
            pk[dd >> 1] = (uint32_t)f2bf(o0) | ((uint32_t)f2bf(o1) << 16);
        }
        uint4 ov;
        ov.x = pk[0]; ov.y = pk[1]; ov.z = pk[2]; ov.w = pk[3];
        *(uint4*)(qrow + c * 8) = ov;
    }
}

// ---------------------------------------------------------------------------
extern "C" void kernel_launch(void* const* d_in, const int* in_sizes, int n_in,
                              void* d_out, int out_size, void* d_ws, size_t ws_size,
                              hipStream_t stream) {
    (void)in_sizes; (void)n_in; (void)out_size; (void)ws_size;

    // workspace layout (256B-aligned), total ~94.7 MB
    char* ws = (char*)d_ws;
    int* flag      = (int*)(ws + 0);
    float* Mg      = (float*)(ws + 256);        // 409,600 B scratch (serial reuse)
    float* AcQ     = (float*)(ws + 409856);
    float* AcK     = (float*)(ws + 819456);
    float* AcV     = (float*)(ws + 966912);
    float* AcO     = (float*)(ws + 1114368);
    float* BcQ     = (float*)(ws + 1523968);
    float* BcK     = (float*)(ws + 1605888);
    float* BcV     = (float*)(ws + 1655040);
    float* BcO     = (float*)(ws + 1704192);
    uint16_t* WqT  = (uint16_t*)(ws + 1786112);   // [1280][1280]
    uint16_t* WkT  = (uint16_t*)(ws + 5062912);   // [1280][768]
    uint16_t* WvT  = (uint16_t*)(ws + 7028992);
    uint16_t* WoT  = (uint16_t*)(ws + 8995072);   // [1280][1280]
    uint16_t* kb   = (uint16_t*)(ws + 12271872);  // [616][1280]
    uint16_t* vb   = (uint16_t*)(ws + 13848832);
    uint16_t* qb   = (uint16_t*)(ws + 15425792);  // [32768][1280]

    detect_dtype<<<1, 64, 0, stream>>>((const uint16_t*)d_in[0], flag);

    // Cayley (Newton-Schulz), dual-launched per dtype
#define CAYLEY(idx, dst, nb, n)                                                              \
    cayley_ns<uint16_t><<<nb, 256, 0, stream>>>((const uint16_t*)d_in[idx], dst, Mg, n, flag, 1); \
    cayley_ns<float><<<nb, 256, 0, stream>>>((const float*)d_in[idx], dst, Mg, n, flag, 0)
    CAYLEY(2, AcQ, 16, 80);
    CAYLEY(3, BcQ, 80, 16);
    CAYLEY(4, AcK, 16, 48);
    CAYLEY(5, BcK, 48, 16);
    CAYLEY(6, AcV, 16, 48);
    CAYLEY(7, BcV, 48, 16);
    CAYLEY(8, AcO, 16, 80);
    CAYLEY(9, BcO, 80, 16);
#undef CAYLEY

    // Fold Monarch + W^T + scale -> WeffT (bf16), dual-launched
#define WEFF(widx, Ac, Bc, sidx, dst, bdim, Din)                                  \
    build_weff2<uint16_t><<<1280, 256, 0, stream>>>((const uint16_t*)d_in[widx], Ac, Bc, \
        (const uint16_t*)d_in[sidx], dst, bdim, Din, flag, 1);                    \
    build_weff2<float><<<1280, 256, 0, stream>>>((const float*)d_in[widx], Ac, Bc,       \
        (const float*)d_in[sidx], dst, bdim, Din, flag, 0)
    WEFF(10, AcQ, BcQ, 15, WqT, 80, 1280);
    WEFF(11, AcK, BcK, 16, WkT, 48, 768);
    WEFF(12, AcV, BcV, 17, WvT, 48, 768);
    WEFF(13, AcO, BcO, 18, WoT, 80, 1280);
#undef WEFF

    // Projections (C always bf16 internal)
    gemm_bt<uint16_t><<<dim3(10, 256), 256, 0, stream>>>((const uint16_t*)d_in[0], WqT, qb,
                                                         nullptr, 32768, 1280, 1280, flag, 1, 0);
    gemm_bt<float><<<dim3(10, 256), 256, 0, stream>>>((const float*)d_in[0], WqT, qb,
                                                      nullptr, 32768, 1280, 1280, flag, 0, 0);
    gemm_bt<uint16_t><<<dim3(10, 5), 256, 0, stream>>>((const uint16_t*)d_in[1], WkT, kb,
                                                       nullptr, 616, 1280, 768, flag, 1, 0);
    gemm_bt<float><<<dim3(10, 5), 256, 0, stream>>>((const float*)d_in[1], WkT, kb,
                                                    nullptr, 616, 1280, 768, flag, 0, 0);
    gemm_bt<uint16_t><<<dim3(10, 5), 256, 0, stream>>>((const uint16_t*)d_in[1], WvT, vb,
                                                       nullptr, 616, 1280, 768, flag, 1, 0);
    gemm_bt<float><<<dim3(10, 5), 256, 0, stream>>>((const float*)d_in[1], WvT, vb,
                                                    nullptr, 616, 1280, 768, flag, 0, 0);

    // Attention (in-place on qb, always bf16)
    attn_fused<<<dim3(16, 20, 8), 256, 0, stream>>>(kb, vb, qb, 8, 4096);

    // Output projection + bias -> d_out, out dtype follows flag
    gemm_bt<uint16_t><<<dim3(10, 256), 256, 0, stream>>>(qb, WoT, d_out, d_in[14],
                                                         32768, 1280, 1280, flag, -1, 1);
}